// Round 6
// baseline (102.861 us; speedup 1.0000x reference)
//
#include <hip/hip_runtime.h>
#include <hip/hip_bf16.h>
#include <math.h>

#define Bn 128
#define Tn 512
#define Cn 256
#define Hn 64
#define NQKV 192
#define SCL 0.18033688011112042f   // log2(e)/8 : exp2-domain softmax scale

typedef __attribute__((ext_vector_type(8))) short short8v;   // 8 bf16
typedef __attribute__((ext_vector_type(4))) float float4v;   // MFMA C/D

__device__ __forceinline__ ushort f2bf(float f) {
    __hip_bfloat16 h = __float2bfloat16(f);   // RNE
    return *reinterpret_cast<ushort*>(&h);
}

// ---- LDS layout (byte offsets), total 163840 B = 160 KiB exactly ----
// Ks[512][64] bf16 swizzled   @ 0       (64 KB)  key-major, [t][h]
// Vt[64][512] bf16 swizzled   @ 65536   (64 KB)  [h][t]
// xq[32][256] bf16 swizzled   @ 131072  (16 KB)  x-chunk staging
// qp: 8 waves x 2 KB          @ 147456  (16 KB)  q-bounce (phase A) / P (phase B)
#define KS_OFF 0
#define VT_OFF 65536
#define XQ_OFF 131072
#define QP_OFF 147456

__device__ __forceinline__ int ks_byte(int t, int h) {
    return KS_OFF + ((t * 128 + h * 2) ^ ((t & 7) << 4));
}
__device__ __forceinline__ int vt_byte(int h, int t) {
    return VT_OFF + ((h * 1024 + t * 2) ^ ((h & 7) << 4));
}
__device__ __forceinline__ int xq_byte(int r, int c) {
    return XQ_OFF + ((r * 512 + c * 2) ^ ((r & 7) << 4));
}
__device__ __forceinline__ int qp_byte(int wv, int r, int c) {
    return QP_OFF + wv * 2048 + ((r * 128 + c * 2) ^ ((r & 7) << 4));
}

// ---------------------------------------------------------------------------
// Prep: WcT[m*64+h][c] = W_m[c][h] as bf16 (row-major [col][k]). -> d_ws
// ---------------------------------------------------------------------------
__global__ __launch_bounds__(256) void prep_w_kernel(
    const float* __restrict__ Wq, const float* __restrict__ Wk,
    const float* __restrict__ Wv, ushort* __restrict__ wcT)
{
    const int row = blockIdx.x;          // 0..191
    const int c   = threadIdx.x;         // 0..255
    const float* W = (row < 64) ? Wq : (row < 128) ? Wk : Wv;
    const int h = row & 63;
    wcT[row * Cn + c] = f2bf(W[c * Hn + h]);
}

// ---------------------------------------------------------------------------
// Fused QKV + causal flash attention. Grid (2, 128): block (h, b) handles
// q rows [h*256, h*256+256) of batch b; builds K/Vt for keys [0, (h+1)*256)
// in LDS (phase A, x streamed in 32-row chunks), also computes its q rows'
// fragments into registers. Phase B: barrier-free per-wave flash attention
// entirely from LDS.  8 waves x 64 lanes; wave owns 16 q rows per qtile.
// MFMA 16x16x32_bf16 layouts as verified in rounds 2-5:
//   A: row=lane&15, k=(lane>>4)*8+j ; B: col=lane&15, same k
//   D: col=lane&15, row=(lane>>4)*4+reg
// ---------------------------------------------------------------------------
__global__ __launch_bounds__(512, 2) void fused_attn_kernel(
    const float* __restrict__ x, const ushort* __restrict__ wcT,
    float* __restrict__ out)
{
    __shared__ char lds[163840];
    const int tid  = threadIdx.x;
    const int hblk = blockIdx.x;          // 0,1 : which T-half of q rows
    const int b    = blockIdx.y;          // batch
    const int lane = tid & 63;
    const int wv   = tid >> 6;            // 0..7
    const int lr   = lane & 15;
    const int hi   = lane >> 4;

    const int kvn   = (hblk + 1) * 256;   // keys this block needs
    const int nch   = kvn >> 5;           // 8 or 16 chunks of 32 rows
    const int cq0   = hblk * 8;           // first chunk containing our q rows
    const int qrow0 = hblk * 256;

    const float* xb = x + (long)b * Tn * Cn;

    const int mi = wv >> 2;               // 0..1 : 16-row strip within chunk
    const int nq = wv & 3;                // 0..3 : which 32-col group of K|V

    short8v qa[2][2];                     // [qtile][ks] q A-fragments

    // ---------------- phase A: stream x, build K/Vt in LDS, prep q ----------
    float4 xr[4], xn[4];
    {
        const float4* x4 = (const float4*)xb;
        #pragma unroll
        for (int i = 0; i < 4; ++i) xr[i] = x4[tid + i * 512];
    }

    for (int c = 0; c < nch; ++c) {
        // stage current 32-row chunk (cvt fp32->bf16, swizzled)
        #pragma unroll
        for (int i = 0; i < 4; ++i) {
            int idx = tid + i * 512;          // 0..2047
            int r   = idx >> 6;               // 0..31
            int c4  = idx & 63;
            union { ushort u[4]; uint2 p; } pk;
            pk.u[0] = f2bf(xr[i].x); pk.u[1] = f2bf(xr[i].y);
            pk.u[2] = f2bf(xr[i].z); pk.u[3] = f2bf(xr[i].w);
            *(uint2*)(lds + xq_byte(r, c4 * 4)) = pk.p;
        }
        __syncthreads();

        // prefetch next chunk (hides HBM latency under compute)
        if (c + 1 < nch) {
            const float4* x4 = (const float4*)(xb + (long)(c + 1) * 32 * Cn);
            #pragma unroll
            for (int i = 0; i < 4; ++i) xn[i] = x4[tid + i * 512];
        }

        // K|V projection: wave does rows mi*16..+16, W-cols 64+nq*32..+32
        float4v acc[2];
        acc[0] = (float4v){0.f, 0.f, 0.f, 0.f};
        acc[1] = acc[0];
        #pragma unroll
        for (int ks = 0; ks < 8; ++ks) {
            short8v a = *(const short8v*)(lds + xq_byte(mi * 16 + lr, ks * 32 + hi * 8));
            #pragma unroll
            for (int nn = 0; nn < 2; ++nn) {
                short8v bb = *(const short8v*)(wcT +
                    (long)(64 + (nq * 2 + nn) * 16 + lr) * Cn + ks * 32 + hi * 8);
                acc[nn] = __builtin_amdgcn_mfma_f32_16x16x32_bf16(a, bb, acc[nn], 0, 0, 0);
            }
        }
        {
            int t0 = c * 32 + mi * 16 + hi * 4;
            if (nq < 2) {                      // K columns: Ks[t][h], scalar
                #pragma unroll
                for (int nn = 0; nn < 2; ++nn) {
                    int h = (nq * 2 + nn) * 16 + lr;
                    #pragma unroll
                    for (int reg = 0; reg < 4; ++reg)
                        *(ushort*)(lds + ks_byte(t0 + reg, h)) = f2bf(acc[nn][reg]);
                }
            } else {                           // V columns: Vt[h][t], b64 pack
                #pragma unroll
                for (int nn = 0; nn < 2; ++nn) {
                    int h = ((nq - 2) * 2 + nn) * 16 + lr;
                    ushort4 pk;
                    pk.x = f2bf(acc[nn][0]); pk.y = f2bf(acc[nn][1]);
                    pk.z = f2bf(acc[nn][2]); pk.w = f2bf(acc[nn][3]);
                    *(ushort4*)(lds + vt_byte(h, t0)) = pk;
                }
            }
        }

        // q-prep: 2 waves per chunk own this chunk's q rows
        if (c >= cq0) {
            int rel = c - cq0;                 // 0..7
            if ((wv >> 1) == (rel & 3)) {
                int qt2  = rel >> 2;           // 0..1
                int rloc = (wv & 1) * 16;      // local row base in chunk
                float4v qacc[4];
                #pragma unroll
                for (int n = 0; n < 4; ++n) qacc[n] = (float4v){0.f, 0.f, 0.f, 0.f};
                #pragma unroll
                for (int ks = 0; ks < 8; ++ks) {
                    short8v a = *(const short8v*)(lds + xq_byte(rloc + lr, ks * 32 + hi * 8));
                    #pragma unroll
                    for (int n = 0; n < 4; ++n) {
                        short8v bb = *(const short8v*)(wcT +
                            (long)(n * 16 + lr) * Cn + ks * 32 + hi * 8);
                        qacc[n] = __builtin_amdgcn_mfma_f32_16x16x32_bf16(a, bb, qacc[n], 0, 0, 0);
                    }
                }
                // D-layout -> A-layout bounce through this wave's qp slice
                #pragma unroll
                for (int n = 0; n < 4; ++n)
                    #pragma unroll
                    for (int reg = 0; reg < 4; ++reg)
                        *(ushort*)(lds + qp_byte(wv, hi * 4 + reg, n * 16 + lr)) =
                            f2bf(qacc[n][reg]);
                #pragma unroll
                for (int k2 = 0; k2 < 2; ++k2)
                    qa[qt2][k2] = *(const short8v*)(lds + qp_byte(wv, lr, k2 * 32 + hi * 8));
            }
        }
        __syncthreads();
        if (c + 1 < nch) {
            #pragma unroll
            for (int i = 0; i < 4; ++i) xr[i] = xn[i];
        }
    }
    // K/Vt complete and visible (trailing barrier of last chunk)

    // ---------------- phase B: barrier-free flash attention ----------------
    const long obase = (long)b * Tn * Hn;
    #pragma unroll
    for (int qt2 = 0; qt2 < 2; ++qt2) {
        const int r0    = qrow0 + qt2 * 128 + wv * 16;   // wave's first q row
        const int mrow0 = r0 + hi * 4;                   // lane's first q row
        const int ktp   = r0 >> 6;                       // partial (last) tile

        float4v o[4];
        float m[4], l[4];
        #pragma unroll
        for (int n = 0; n < 4; ++n) o[n] = (float4v){0.f, 0.f, 0.f, 0.f};
        #pragma unroll
        for (int reg = 0; reg < 4; ++reg) { m[reg] = -INFINITY; l[reg] = 0.f; }

        for (int kt = 0; kt <= ktp; ++kt) {
            // ---- QK^T ----
            float4v s4[4];
            #pragma unroll
            for (int n = 0; n < 4; ++n) s4[n] = (float4v){0.f, 0.f, 0.f, 0.f};
            #pragma unroll
            for (int k2 = 0; k2 < 2; ++k2) {
                short8v a = qa[qt2][k2];
                #pragma unroll
                for (int n = 0; n < 4; ++n) {
                    short8v bb = *(const short8v*)(lds +
                        ks_byte(kt * 64 + n * 16 + lr, k2 * 32 + hi * 8));
                    s4[n] = __builtin_amdgcn_mfma_f32_16x16x32_bf16(a, bb, s4[n], 0, 0, 0);
                }
            }

            // ---- exp2-domain scale + causal mask (partial tile only) ----
            if (kt == ktp) {
                #pragma unroll
                for (int n = 0; n < 4; ++n) {
                    int kcol = kt * 64 + n * 16 + lr;
                    #pragma unroll
                    for (int reg = 0; reg < 4; ++reg) {
                        float y = s4[n][reg] * SCL;
                        s4[n][reg] = (kcol <= mrow0 + reg) ? y : -INFINITY;
                    }
                }
            } else {
                #pragma unroll
                for (int n = 0; n < 4; ++n)
                    #pragma unroll
                    for (int reg = 0; reg < 4; ++reg) s4[n][reg] *= SCL;
            }

            // ---- online softmax ----
            #pragma unroll
            for (int reg = 0; reg < 4; ++reg) {
                float mx = fmaxf(fmaxf(s4[0][reg], s4[1][reg]),
                                 fmaxf(s4[2][reg], s4[3][reg]));
                mx = fmaxf(mx, __shfl_xor(mx, 1));
                mx = fmaxf(mx, __shfl_xor(mx, 2));
                mx = fmaxf(mx, __shfl_xor(mx, 4));
                mx = fmaxf(mx, __shfl_xor(mx, 8));
                float mN = fmaxf(m[reg], mx);
                float sc = exp2f(m[reg] - mN);           // first tile: 0
                float ps = 0.f;
                #pragma unroll
                for (int n = 0; n < 4; ++n) {
                    float p = exp2f(s4[n][reg] - mN);    // masked: 0
                    s4[n][reg] = p;
                    ps += p;
                }
                ps += __shfl_xor(ps, 1);
                ps += __shfl_xor(ps, 2);
                ps += __shfl_xor(ps, 4);
                ps += __shfl_xor(ps, 8);
                l[reg] = l[reg] * sc + ps;
                m[reg] = mN;
                #pragma unroll
                for (int n = 0; n < 4; ++n) o[n][reg] *= sc;
            }

            // ---- P -> bf16 in this wave's qp slice (intra-wave only) ----
            #pragma unroll
            for (int n = 0; n < 4; ++n)
                #pragma unroll
                for (int reg = 0; reg < 4; ++reg)
                    *(ushort*)(lds + qp_byte(wv, hi * 4 + reg, n * 16 + lr)) =
                        f2bf(s4[n][reg]);

            // ---- PV ----
            #pragma unroll
            for (int k2 = 0; k2 < 2; ++k2) {
                short8v a = *(const short8v*)(lds + qp_byte(wv, lr, k2 * 32 + hi * 8));
                #pragma unroll
                for (int n = 0; n < 4; ++n) {
                    short8v bb = *(const short8v*)(lds +
                        vt_byte(n * 16 + lr, kt * 64 + k2 * 32 + hi * 8));
                    o[n] = __builtin_amdgcn_mfma_f32_16x16x32_bf16(a, bb, o[n], 0, 0, 0);
                }
            }
        }

        // ---- epilogue ----
        #pragma unroll
        for (int reg = 0; reg < 4; ++reg) {
            float inv = 1.0f / l[reg];
            float* orow = out + obase + (long)(mrow0 + reg) * Hn;
            #pragma unroll
            for (int n = 0; n < 4; ++n)
                orow[n * 16 + lr] = o[n][reg] * inv;
        }
    }
}

extern "C" void kernel_launch(void* const* d_in, const int* in_sizes, int n_in,
                              void* d_out, int out_size, void* d_ws, size_t ws_size,
                              hipStream_t stream) {
    const float* x  = (const float*)d_in[0];
    const float* Wq = (const float*)d_in[1];
    const float* Wk = (const float*)d_in[2];
    const float* Wv = (const float*)d_in[3];
    float* out = (float*)d_out;

    ushort* wcT = (ushort*)d_ws;   // 98 KB of workspace

    prep_w_kernel<<<dim3(NQKV), 256, 0, stream>>>(Wq, Wk, Wv, wcT);
    fused_attn_kernel<<<dim3(2, Bn), 512, 0, stream>>>(x, wcT, out);
}

// Round 7
// 65.752 us; speedup vs baseline: 1.5644x; 1.5644x over previous
//
#include <hip/hip_runtime.h>
#include <hip/hip_bf16.h>
#include <math.h>

#define Bn 128
#define Tn 512
#define Cn 256
#define Hn 64
#define NQKV 192
#define HP2 72          // padded bf16 LDS stride for attn tiles (144 B)
#define SCL 0.18033688011112042f   // log2(e)/8 : exp2-domain softmax scale

typedef __attribute__((ext_vector_type(8))) short short8v;   // 8 bf16
typedef __attribute__((ext_vector_type(4))) float float4v;   // MFMA C/D

__device__ __forceinline__ ushort f2bf(float f) {
    __hip_bfloat16 h = __float2bfloat16(f);   // RNE
    return *reinterpret_cast<ushort*>(&h);
}

// ---------------------------------------------------------------------------
// Prep: WcT[m*64+h][c] = W_m[c][h] as bf16 (row-major [col][k]).
// ---------------------------------------------------------------------------
__global__ __launch_bounds__(256) void prep_w_kernel(
    const float* __restrict__ Wq, const float* __restrict__ Wk,
    const float* __restrict__ Wv, ushort* __restrict__ wcT)
{
    const int row = blockIdx.x;          // 0..191
    const int c   = threadIdx.x;         // 0..255
    const float* W = (row < 64) ? Wq : (row < 128) ? Wk : Wv;
    const int h = row & 63;
    wcT[row * Cn + c] = f2bf(W[c * Hn + h]);
}

// ---------------------------------------------------------------------------
// QKV GEMM v3: 1024 blocks x 256 thr (4 waves), 64 rows/block, 4 blocks/CU.
// x tile staged once in swizzled LDS (32 KB); W fragments read from L2 in
// the MFMA loop (no W staging, no persistent W regs). Wave (wr=wv>>1,
// wc=wv&1): rows wr*32 (2 strips), cols wc*96 (6 n-frags). q/k: scalar
// stores (lines fully covered -> L2 merge). V: bounce via swizzled LDS ->
// coalesced uint4 stores to vT[b][h][t]. Exactly 2 barriers per block;
// inter-block overlap (4/CU) hides stage/store latency.
// ---------------------------------------------------------------------------
__global__ __launch_bounds__(256, 4) void qkv_mfma_kernel(
    const float* __restrict__ x, const ushort* __restrict__ wcT,
    ushort* __restrict__ q, ushort* __restrict__ k, ushort* __restrict__ vT)
{
    __shared__ ushort xs[64 * 256];        // 32 KB, XOR-swizzled bf16 x-tile
    __shared__ ushort Vb[64 * 64];         // 8 KB, XOR-swizzled V bounce [h][t]
    char* xb = (char*)xs;
    char* vb = (char*)Vb;

    const int tid  = threadIdx.x;
    const int lane = tid & 63;
    const int wv   = tid >> 6;             // 0..3
    const int lr   = lane & 15;
    const int hi   = lane >> 4;
    const int wr   = wv >> 1;              // 0..1 : 32-row strip
    const int wc   = wv & 1;               // 0..1 : 96-col strip
    const long rows0 = (long)blockIdx.x * 64;

    // ---- stage x tile: 16 float4/thread, cvt -> swizzled LDS ----
    {
        const float4* x4 = (const float4*)(x + rows0 * Cn);
        float4 xr[16];
        #pragma unroll
        for (int i = 0; i < 16; ++i) xr[i] = x4[tid + i * 256];
        #pragma unroll
        for (int i = 0; i < 16; ++i) {
            int idx = tid + i * 256;           // 0..4095 uint2 slots
            int r   = idx >> 6;                // 0..63
            int c4  = idx & 63;
            union { ushort u[4]; uint2 p; } pk;
            pk.u[0] = f2bf(xr[i].x); pk.u[1] = f2bf(xr[i].y);
            pk.u[2] = f2bf(xr[i].z); pk.u[3] = f2bf(xr[i].w);
            int off = (r * 512 + c4 * 8) ^ ((r & 7) << 4);
            *(uint2*)(xb + off) = pk.p;
        }
    }
    __syncthreads();

    // ---- MFMA: 2 m-strips x 6 n-frags, W from L2 ----
    float4v acc[2][6];
    #pragma unroll
    for (int s = 0; s < 2; ++s)
        #pragma unroll
        for (int n = 0; n < 6; ++n) acc[s][n] = (float4v){0.f, 0.f, 0.f, 0.f};

    const int r0 = wr * 32 + lr;
    const int r1 = r0 + 16;
    const ushort* bbase = wcT + (long)(wc * 96 + lr) * Cn + hi * 8;
    #pragma unroll
    for (int ks = 0; ks < 8; ++ks) {
        short8v a0 = *(const short8v*)(xb + ((r0 * 512 + ks * 64 + hi * 16) ^ ((r0 & 7) << 4)));
        short8v a1 = *(const short8v*)(xb + ((r1 * 512 + ks * 64 + hi * 16) ^ ((r1 & 7) << 4)));
        #pragma unroll
        for (int n = 0; n < 6; ++n) {
            short8v b = *(const short8v*)(bbase + (long)n * 16 * Cn + ks * 32);
            acc[0][n] = __builtin_amdgcn_mfma_f32_16x16x32_bf16(a0, b, acc[0][n], 0, 0, 0);
            acc[1][n] = __builtin_amdgcn_mfma_f32_16x16x32_bf16(a1, b, acc[1][n], 0, 0, 0);
        }
    }

    // ---- stores: q/k scalar (full-line coverage within wave); V -> Vb ----
    #pragma unroll
    for (int s = 0; s < 2; ++s) {
        const int tl = wr * 32 + s * 16 + hi * 4;      // local row (+reg)
        #pragma unroll
        for (int n = 0; n < 6; ++n) {
            int col = wc * 96 + n * 16 + lr;
            if (col < 128) {
                ushort* outp = (col < 64) ? q : k;
                int hcol = col & 63;
                #pragma unroll
                for (int reg = 0; reg < 4; ++reg)
                    outp[(rows0 + tl + reg) * Hn + hcol] = f2bf(acc[s][n][reg]);
            } else {
                int h = col - 128;
                ushort4 pk;
                pk.x = f2bf(acc[s][n][0]); pk.y = f2bf(acc[s][n][1]);
                pk.z = f2bf(acc[s][n][2]); pk.w = f2bf(acc[s][n][3]);
                int off = (h * 128 + tl * 2) ^ ((h & 7) << 4);
                *(ushort4*)(vb + off) = pk;
            }
        }
    }
    __syncthreads();

    // ---- coalesced vT store: vT[b][h][t], 2 uint4/thread ----
    {
        const int bb = (int)(rows0 >> 9);
        const int t0 = (int)(rows0 & 511);
        #pragma unroll
        for (int i = 0; i < 2; ++i) {
            int idx = tid + i * 256;               // 0..511
            int h   = idx >> 3;
            int c8  = idx & 7;
            int off = (h * 128 + c8 * 16) ^ ((h & 7) << 4);
            *(uint4*)(vT + ((long)bb * Hn + h) * Tn + t0 + c8 * 8) =
                *(const uint4*)(vb + off);
        }
    }
}

// ---------------------------------------------------------------------------
// MFMA flash attention, 128-row Q tile, 8 waves (512 thr). Unchanged (r4).
// ---------------------------------------------------------------------------
__global__ __launch_bounds__(512) void attn_mfma_kernel(
    const ushort* __restrict__ q, const ushort* __restrict__ k,
    const ushort* __restrict__ vT, float* __restrict__ out)
{
    __shared__ ushort Ks[64 * HP2];        // [key s][h]
    __shared__ ushort Vt[64 * HP2];        // [h][key s]
    __shared__ ushort Pl[8][16 * HP2];     // per-wave P rows

    const int tid = threadIdx.x;
    const int f   = blockIdx.x;            // 0..511
    const int c   = f & 255;
    const int b   = c >> 1;
    const int par = c & 1;
    const int qtp = (f < 256) ? par : (3 - par);   // q-tile 0..3
    const int ntiles = 2 * qtp + 2;

    const long base  = (long)b * Tn * Hn;
    const int lane = tid & 63;
    const int wv   = tid >> 6;             // 0..7
    const int lr   = lane & 15;
    const int hi   = lane >> 4;

    const int qrow_g = qtp * 128 + wv * 16;
    const int mrow0  = qrow_g + hi * 4;

    short8v qa[2];
    {
        const ushort* qp = q + base + (long)(qrow_g + lr) * Hn + hi * 8;
        qa[0] = *(const short8v*)(qp);
        qa[1] = *(const short8v*)(qp + 32);
    }

    const int sr  = tid >> 3;
    const int sc8 = tid & 7;
    uint4 kreg = *(const uint4*)(k + base + (long)sr * Hn + sc8 * 8);
    uint4 vreg = *(const uint4*)(vT + base + (long)sr * Tn + sc8 * 8);

    float4v o[4];
    #pragma unroll
    for (int n = 0; n < 4; ++n) o[n] = (float4v){0.f, 0.f, 0.f, 0.f};
    float m[4], l[4];
    #pragma unroll
    for (int reg = 0; reg < 4; ++reg) { m[reg] = -INFINITY; l[reg] = 0.f; }

    for (int kt = 0; kt < ntiles; ++kt) {
        __syncthreads();
        *(uint4*)&Ks[sr * HP2 + sc8 * 8] = kreg;
        *(uint4*)&Vt[sr * HP2 + sc8 * 8] = vreg;
        __syncthreads();
        if (kt + 1 < ntiles) {
            kreg = *(const uint4*)(k  + base + (long)((kt + 1) * 64 + sr) * Hn + sc8 * 8);
            vreg = *(const uint4*)(vT + base + (long)sr * Tn + (kt + 1) * 64 + sc8 * 8);
        }
        if (kt * 64 > qrow_g + 15) continue;

        float4v s4[4];
        #pragma unroll
        for (int n = 0; n < 4; ++n) s4[n] = (float4v){0.f, 0.f, 0.f, 0.f};
        #pragma unroll
        for (int ks = 0; ks < 2; ++ks) {
            short8v a = qa[ks];
            #pragma unroll
            for (int n = 0; n < 4; ++n) {
                short8v bb = *(const short8v*)&Ks[(n * 16 + lr) * HP2 + ks * 32 + hi * 8];
                s4[n] = __builtin_amdgcn_mfma_f32_16x16x32_bf16(a, bb, s4[n], 0, 0, 0);
            }
        }

        const bool partial = (kt * 64 + 63 > qrow_g);
        if (partial) {
            #pragma unroll
            for (int n = 0; n < 4; ++n) {
                int kcol = kt * 64 + n * 16 + lr;
                #pragma unroll
                for (int reg = 0; reg < 4; ++reg) {
                    float y = s4[n][reg] * SCL;
                    s4[n][reg] = (kcol <= mrow0 + reg) ? y : -INFINITY;
                }
            }
        } else {
            #pragma unroll
            for (int n = 0; n < 4; ++n)
                #pragma unroll
                for (int reg = 0; reg < 4; ++reg) s4[n][reg] *= SCL;
        }

        #pragma unroll
        for (int reg = 0; reg < 4; ++reg) {
            float mx = fmaxf(fmaxf(s4[0][reg], s4[1][reg]),
                             fmaxf(s4[2][reg], s4[3][reg]));
            mx = fmaxf(mx, __shfl_xor(mx, 1));
            mx = fmaxf(mx, __shfl_xor(mx, 2));
            mx = fmaxf(mx, __shfl_xor(mx, 4));
            mx = fmaxf(mx, __shfl_xor(mx, 8));
            float mN = fmaxf(m[reg], mx);
            float sc = exp2f(m[reg] - mN);
            float ps = 0.f;
            #pragma unroll
            for (int n = 0; n < 4; ++n) {
                float p = exp2f(s4[n][reg] - mN);
                s4[n][reg] = p;
                ps += p;
            }
            ps += __shfl_xor(ps, 1);
            ps += __shfl_xor(ps, 2);
            ps += __shfl_xor(ps, 4);
            ps += __shfl_xor(ps, 8);
            l[reg] = l[reg] * sc + ps;
            m[reg] = mN;
            #pragma unroll
            for (int n = 0; n < 4; ++n) o[n][reg] *= sc;
        }

        #pragma unroll
        for (int n = 0; n < 4; ++n)
            #pragma unroll
            for (int reg = 0; reg < 4; ++reg)
                Pl[wv][(hi * 4 + reg) * HP2 + n * 16 + lr] = f2bf(s4[n][reg]);

        #pragma unroll
        for (int ks = 0; ks < 2; ++ks) {
            short8v a = *(const short8v*)&Pl[wv][lr * HP2 + ks * 32 + hi * 8];
            #pragma unroll
            for (int n = 0; n < 4; ++n) {
                short8v bb = *(const short8v*)&Vt[(n * 16 + lr) * HP2 + ks * 32 + hi * 8];
                o[n] = __builtin_amdgcn_mfma_f32_16x16x32_bf16(a, bb, o[n], 0, 0, 0);
            }
        }
    }

    #pragma unroll
    for (int reg = 0; reg < 4; ++reg) {
        float inv = 1.0f / l[reg];
        float* orow = out + base + (long)(mrow0 + reg) * Hn;
        #pragma unroll
        for (int n = 0; n < 4; ++n)
            orow[n * 16 + lr] = o[n][reg] * inv;
    }
}

extern "C" void kernel_launch(void* const* d_in, const int* in_sizes, int n_in,
                              void* d_out, int out_size, void* d_ws, size_t ws_size,
                              hipStream_t stream) {
    const float* x  = (const float*)d_in[0];
    const float* Wq = (const float*)d_in[1];
    const float* Wk = (const float*)d_in[2];
    const float* Wv = (const float*)d_in[3];
    float* out = (float*)d_out;

    const size_t n = (size_t)Bn * Tn * Hn;
    ushort* qws = (ushort*)d_ws;
    ushort* kws = qws + n;
    ushort* vTs = kws + n;

    // WcT (bf16, 98 KB) in d_out head: consumed by qkv_mfma, then fully
    // overwritten by attn's epilogue.
    ushort* wcT = (ushort*)d_out;

    prep_w_kernel<<<dim3(NQKV), 256, 0, stream>>>(Wq, Wk, Wv, wcT);
    qkv_mfma_kernel<<<dim3(Bn * Tn / 64), 256, 0, stream>>>(x, wcT, qws, kws, vTs);
    attn_mfma_kernel<<<dim3(512), 512, 0, stream>>>(qws, kws, vTs, out);
}

// Round 8
// 52.376 us; speedup vs baseline: 1.9639x; 1.2554x over previous
//
#include <hip/hip_runtime.h>
#include <hip/hip_bf16.h>
#include <math.h>

#define Bn 128
#define Tn 512
#define Cn 256
#define Hn 64
#define NQKV 192
#define HP2 72          // padded bf16 LDS stride for attn tiles (144 B)
#define SCL 0.18033688011112042f   // log2(e)/8 : exp2-domain softmax scale

typedef __attribute__((ext_vector_type(8))) short short8v;   // 8 bf16
typedef __attribute__((ext_vector_type(4))) float float4v;   // MFMA C/D

__device__ __forceinline__ ushort f2bf(float f) {
    __hip_bfloat16 h = __float2bfloat16(f);   // RNE
    return *reinterpret_cast<ushort*>(&h);
}

// ---------------------------------------------------------------------------
// Prep: WcT[col][c] = W_m[c][h] as bf16, PRE-SWIZZLED within each 512 B row
// (ushort idx c ^ ((col&7)<<3)  ==  byte (c*2) ^ ((col&7)<<4)) so that a
// linear global_load_lds copy yields an XOR-swizzled LDS tile (m173 pattern).
// ---------------------------------------------------------------------------
__global__ __launch_bounds__(256) void prep_w_kernel(
    const float* __restrict__ Wq, const float* __restrict__ Wk,
    const float* __restrict__ Wv, ushort* __restrict__ wcT)
{
    const int col = blockIdx.x;          // 0..191
    const int c   = threadIdx.x;         // 0..255
    const float* W = (col < 64) ? Wq : (col < 128) ? Wk : Wv;
    const int h = col & 63;
    wcT[col * Cn + (c ^ ((col & 7) << 3))] = f2bf(W[c * Hn + h]);
}

// ---------------------------------------------------------------------------
// QKV GEMM v4: 2048 blocks x 256 thr (4 waves), 2 blocks/CU (80 KB LDS,
// launch_bounds(256,2) -> VGPR<=128 so staging + inner loop can pipeline).
// Block = 64 rows x 96 cols (nh = N-half). blockIdx mapping puts the two
// nh-halves of a row-tile 8 apart -> same XCD (round-robin) -> second
// half's x read hits L2. W-half staged via global_load_lds (pre-swizzled
// source -> swizzled LDS, conflict-free b128 reads). Wave (wr=wv>>1,
// wc=wv&1): rows wr*32, cols wc*48 (3 n-frags).
// ---------------------------------------------------------------------------
__global__ __launch_bounds__(256, 2) void qkv_mfma_kernel(
    const float* __restrict__ x, const ushort* __restrict__ wcT,
    ushort* __restrict__ q, ushort* __restrict__ k, ushort* __restrict__ vT)
{
    __shared__ char lds[81920];
    // [0, 49152)      : W-half, 96 rows x 512 B, row-swizzled
    // [49152, 81920)  : x tile, 64 rows x 512 B, row-swizzled; reused as Vb

    const int tid  = threadIdx.x;
    const int lane = tid & 63;
    const int wv   = tid >> 6;             // 0..3
    const int lr   = lane & 15;
    const int hi   = lane >> 4;
    const int wr   = wv >> 1;              // 0..1 : 32-row strip
    const int wc   = wv & 1;               // 0..1 : 48-col strip

    const int bid     = blockIdx.x;
    const int nh      = (bid >> 3) & 1;                   // N-half
    const int rowtile = (bid & 7) | ((bid >> 4) << 3);    // 0..1023
    const long rows0  = (long)rowtile * 64;

    // ---- stage W-half: 48 KB via global_load_lds (12 calls/wave) ----
    {
        const char* gw = (const char*)wcT + (long)nh * 96 * 512;
        #pragma unroll
        for (int i = 0; i < 12; ++i) {
            int off = (wv * 12 + i) * 1024;
            __builtin_amdgcn_global_load_lds(
                (const __attribute__((address_space(1))) unsigned int*)(gw + off + (lane << 4)),
                (__attribute__((address_space(3))) unsigned int*)(lds + off),
                16, 0, 0);
        }
    }

    // ---- stage x tile: 16 float4/thread -> cvt -> swizzled ds_write ----
    {
        const float4* x4 = (const float4*)(x + rows0 * Cn);
        float4 xr[16];
        #pragma unroll
        for (int i = 0; i < 16; ++i) xr[i] = x4[tid + i * 256];
        #pragma unroll
        for (int i = 0; i < 16; ++i) {
            int idx = tid + i * 256;           // 0..4095 uint2 slots
            int r   = idx >> 6;                // 0..63
            int c4  = idx & 63;
            union { ushort u[4]; uint2 p; } pk;
            pk.u[0] = f2bf(xr[i].x); pk.u[1] = f2bf(xr[i].y);
            pk.u[2] = f2bf(xr[i].z); pk.u[3] = f2bf(xr[i].w);
            int off = 49152 + ((r * 512 + c4 * 8) ^ ((r & 7) << 4));
            *(uint2*)(lds + off) = pk.p;
        }
    }
    __syncthreads();   // drains global_load_lds (vmcnt) + ds_writes

    // ---- MFMA: 2 m-strips x 3 n-frags, all operands from LDS ----
    float4v acc[2][3];
    #pragma unroll
    for (int s = 0; s < 2; ++s)
        #pragma unroll
        for (int n = 0; n < 3; ++n) acc[s][n] = (float4v){0.f, 0.f, 0.f, 0.f};

    const int r0 = wr * 32 + lr;
    const int r1 = r0 + 16;
    #pragma unroll
    for (int ks = 0; ks < 8; ++ks) {
        const int kb = ks * 64 + hi * 16;
        short8v a0 = *(const short8v*)(lds + 49152 + ((r0 * 512 + kb) ^ ((r0 & 7) << 4)));
        short8v a1 = *(const short8v*)(lds + 49152 + ((r1 * 512 + kb) ^ ((r1 & 7) << 4)));
        #pragma unroll
        for (int n = 0; n < 3; ++n) {
            int lc = wc * 48 + n * 16 + lr;
            short8v b = *(const short8v*)(lds + lc * 512 + (kb ^ ((lc & 7) << 4)));
            acc[0][n] = __builtin_amdgcn_mfma_f32_16x16x32_bf16(a0, b, acc[0][n], 0, 0, 0);
            acc[1][n] = __builtin_amdgcn_mfma_f32_16x16x32_bf16(a1, b, acc[1][n], 0, 0, 0);
        }
    }

    // ---- stores ----
    if (nh == 0) {
        // cols 0..95: q[h=lc] (lc<64) or k[h=lc-64]
        #pragma unroll
        for (int s = 0; s < 2; ++s) {
            const int tl = wr * 32 + s * 16 + hi * 4;
            #pragma unroll
            for (int n = 0; n < 3; ++n) {
                int lc = wc * 48 + n * 16 + lr;
                ushort* outp = (lc < 64) ? q : k;
                int hcol = lc & 63;
                #pragma unroll
                for (int reg = 0; reg < 4; ++reg)
                    outp[(rows0 + tl + reg) * Hn + hcol] = f2bf(acc[s][n][reg]);
            }
        }
    } else {
        // cols 96..191: k[h=32+lc] (lc<32) or V (h=lc-32) via bounce
        #pragma unroll
        for (int s = 0; s < 2; ++s) {
            const int tl = wr * 32 + s * 16 + hi * 4;
            #pragma unroll
            for (int n = 0; n < 3; ++n) {
                int lc = wc * 48 + n * 16 + lr;
                if (lc < 32) {
                    #pragma unroll
                    for (int reg = 0; reg < 4; ++reg)
                        k[(rows0 + tl + reg) * Hn + 32 + lc] = f2bf(acc[s][n][reg]);
                }
            }
        }
        __syncthreads();   // x tile dead -> reuse as Vb
        #pragma unroll
        for (int s = 0; s < 2; ++s) {
            const int tl = wr * 32 + s * 16 + hi * 4;
            #pragma unroll
            for (int n = 0; n < 3; ++n) {
                int lc = wc * 48 + n * 16 + lr;
                if (lc >= 32) {
                    int h = lc - 32;
                    ushort4 pk;
                    pk.x = f2bf(acc[s][n][0]); pk.y = f2bf(acc[s][n][1]);
                    pk.z = f2bf(acc[s][n][2]); pk.w = f2bf(acc[s][n][3]);
                    int off = 49152 + ((h * 128 + tl * 2) ^ ((h & 7) << 4));
                    *(ushort4*)(lds + off) = pk;
                }
            }
        }
        __syncthreads();
        // coalesced vT store: vT[b][h][t], 2 uint4/thread
        const int bb = (int)(rows0 >> 9);
        const int t0 = (int)(rows0 & 511);
        #pragma unroll
        for (int i = 0; i < 2; ++i) {
            int idx = tid + i * 256;               // 0..511
            int h   = idx >> 3;
            int c8  = idx & 7;
            int off = 49152 + ((h * 128 + c8 * 16) ^ ((h & 7) << 4));
            *(uint4*)(vT + ((long)bb * Hn + h) * Tn + t0 + c8 * 8) =
                *(const uint4*)(lds + off);
        }
    }
}

// ---------------------------------------------------------------------------
// MFMA flash attention, 128-row Q tile, 8 waves (512 thr). Unchanged (r4).
// ---------------------------------------------------------------------------
__global__ __launch_bounds__(512) void attn_mfma_kernel(
    const ushort* __restrict__ q, const ushort* __restrict__ k,
    const ushort* __restrict__ vT, float* __restrict__ out)
{
    __shared__ ushort Ks[64 * HP2];        // [key s][h]
    __shared__ ushort Vt[64 * HP2];        // [h][key s]
    __shared__ ushort Pl[8][16 * HP2];     // per-wave P rows

    const int tid = threadIdx.x;
    const int f   = blockIdx.x;            // 0..511
    const int c   = f & 255;
    const int b   = c >> 1;
    const int par = c & 1;
    const int qtp = (f < 256) ? par : (3 - par);   // q-tile 0..3
    const int ntiles = 2 * qtp + 2;

    const long base  = (long)b * Tn * Hn;
    const int lane = tid & 63;
    const int wv   = tid >> 6;             // 0..7
    const int lr   = lane & 15;
    const int hi   = lane >> 4;

    const int qrow_g = qtp * 128 + wv * 16;
    const int mrow0  = qrow_g + hi * 4;

    short8v qa[2];
    {
        const ushort* qp = q + base + (long)(qrow_g + lr) * Hn + hi * 8;
        qa[0] = *(const short8v*)(qp);
        qa[1] = *(const short8v*)(qp + 32);
    }

    const int sr  = tid >> 3;
    const int sc8 = tid & 7;
    uint4 kreg = *(const uint4*)(k + base + (long)sr * Hn + sc8 * 8);
    uint4 vreg = *(const uint4*)(vT + base + (long)sr * Tn + sc8 * 8);

    float4v o[4];
    #pragma unroll
    for (int n = 0; n < 4; ++n) o[n] = (float4v){0.f, 0.f, 0.f, 0.f};
    float m[4], l[4];
    #pragma unroll
    for (int reg = 0; reg < 4; ++reg) { m[reg] = -INFINITY; l[reg] = 0.f; }

    for (int kt = 0; kt < ntiles; ++kt) {
        __syncthreads();
        *(uint4*)&Ks[sr * HP2 + sc8 * 8] = kreg;
        *(uint4*)&Vt[sr * HP2 + sc8 * 8] = vreg;
        __syncthreads();
        if (kt + 1 < ntiles) {
            kreg = *(const uint4*)(k  + base + (long)((kt + 1) * 64 + sr) * Hn + sc8 * 8);
            vreg = *(const uint4*)(vT + base + (long)sr * Tn + (kt + 1) * 64 + sc8 * 8);
        }
        if (kt * 64 > qrow_g + 15) continue;

        float4v s4[4];
        #pragma unroll
        for (int n = 0; n < 4; ++n) s4[n] = (float4v){0.f, 0.f, 0.f, 0.f};
        #pragma unroll
        for (int ks = 0; ks < 2; ++ks) {
            short8v a = qa[ks];
            #pragma unroll
            for (int n = 0; n < 4; ++n) {
                short8v bb = *(const short8v*)&Ks[(n * 16 + lr) * HP2 + ks * 32 + hi * 8];
                s4[n] = __builtin_amdgcn_mfma_f32_16x16x32_bf16(a, bb, s4[n], 0, 0, 0);
            }
        }

        const bool partial = (kt * 64 + 63 > qrow_g);
        if (partial) {
            #pragma unroll
            for (int n = 0; n < 4; ++n) {
                int kcol = kt * 64 + n * 16 + lr;
                #pragma unroll
                for (int reg = 0; reg < 4; ++reg) {
                    float y = s4[n][reg] * SCL;
                    s4[n][reg] = (kcol <= mrow0 + reg) ? y : -INFINITY;
                }
            }
        } else {
            #pragma unroll
            for (int n = 0; n < 4; ++n)
                #pragma unroll
                for (int reg = 0; reg < 4; ++reg) s4[n][reg] *= SCL;
        }

        #pragma unroll
        for (int reg = 0; reg < 4; ++reg) {
            float mx = fmaxf(fmaxf(s4[0][reg], s4[1][reg]),
                             fmaxf(s4[2][reg], s4[3][reg]));
            mx = fmaxf(mx, __shfl_xor(mx, 1));
            mx = fmaxf(mx, __shfl_xor(mx, 2));
            mx = fmaxf(mx, __shfl_xor(mx, 4));
            mx = fmaxf(mx, __shfl_xor(mx, 8));
            float mN = fmaxf(m[reg], mx);
            float sc = exp2f(m[reg] - mN);
            float ps = 0.f;
            #pragma unroll
            for (int n = 0; n < 4; ++n) {
                float p = exp2f(s4[n][reg] - mN);
                s4[n][reg] = p;
                ps += p;
            }
            ps += __shfl_xor(ps, 1);
            ps += __shfl_xor(ps, 2);
            ps += __shfl_xor(ps, 4);
            ps += __shfl_xor(ps, 8);
            l[reg] = l[reg] * sc + ps;
            m[reg] = mN;
            #pragma unroll
            for (int n = 0; n < 4; ++n) o[n][reg] *= sc;
        }

        #pragma unroll
        for (int n = 0; n < 4; ++n)
            #pragma unroll
            for (int reg = 0; reg < 4; ++reg)
                Pl[wv][(hi * 4 + reg) * HP2 + n * 16 + lr] = f2bf(s4[n][reg]);

        #pragma unroll
        for (int ks = 0; ks < 2; ++ks) {
            short8v a = *(const short8v*)&Pl[wv][lr * HP2 + ks * 32 + hi * 8];
            #pragma unroll
            for (int n = 0; n < 4; ++n) {
                short8v bb = *(const short8v*)&Vt[(n * 16 + lr) * HP2 + ks * 32 + hi * 8];
                o[n] = __builtin_amdgcn_mfma_f32_16x16x32_bf16(a, bb, o[n], 0, 0, 0);
            }
        }
    }

    #pragma unroll
    for (int reg = 0; reg < 4; ++reg) {
        float inv = 1.0f / l[reg];
        float* orow = out + base + (long)(mrow0 + reg) * Hn;
        #pragma unroll
        for (int n = 0; n < 4; ++n)
            orow[n * 16 + lr] = o[n][reg] * inv;
    }
}

extern "C" void kernel_launch(void* const* d_in, const int* in_sizes, int n_in,
                              void* d_out, int out_size, void* d_ws, size_t ws_size,
                              hipStream_t stream) {
    const float* x  = (const float*)d_in[0];
    const float* Wq = (const float*)d_in[1];
    const float* Wk = (const float*)d_in[2];
    const float* Wv = (const float*)d_in[3];
    float* out = (float*)d_out;

    const size_t n = (size_t)Bn * Tn * Hn;
    ushort* qws = (ushort*)d_ws;
    ushort* kws = qws + n;
    ushort* vTs = kws + n;
    ushort* wcT = vTs + n;      // pre-swizzled W, 96 KB in d_ws

    prep_w_kernel<<<dim3(NQKV), 256, 0, stream>>>(Wq, Wk, Wv, wcT);
    qkv_mfma_kernel<<<dim3(2048), 256, 0, stream>>>(x, wcT, qws, kws, vTs);
    attn_mfma_kernel<<<dim3(512), 512, 0, stream>>>(qws, kws, vTs, out);
}